// Round 1
// baseline (121.283 us; speedup 1.0000x reference)
//
#include <hip/hip_runtime.h>
#include <math.h>

// ---------------- constants ----------------
#define P65 65

// Precomputed operator tables (written by init_tables every launch; deterministic).
__device__ float g_R1[4*64*17];   // folded TT64 rearranged per-wave: [w][i<64][m<17], row r=w+4m (<65)
__device__ float g_R2[4*65*16];   // T rearranged per-wave:           [w][i<65][m<16], row r=w+4m (<64)
__device__ float g_G1[64*65];     // G1[j][t] = TT64[t][j]  (tail of step2)
__device__ float g_G2[65*64];     // G2[k1][t] = T[t][k1]   (tail of step3)
__device__ float g_Mp[65*65];     // spectral multiplier with analysis norms folded in; [0][0]=0

__device__ __constant__ float c_DOMAIN[8] = {0.75f,1.0f,0.75f,1.0f,0.75f,1.0f,0.75f,1.0f};

// T[j][k]: k<=32 -> cos(2*pi*j*k/65); k>=33 -> sin(2*pi*j*(k-32)/65)
__device__ inline double Tval(int j, int k) {
  int m = (k <= 32) ? k : (k - 32);
  int prod = (j * m) % 65;                 // exact modular reduction of the angle
  double ang = (6.283185307179586476925286766559 * (double)prod) / 65.0;
  return (k <= 32) ? cos(ang) : sin(ang);
}

__global__ void init_tables() {
  int tid = blockIdx.x*blockDim.x + threadIdx.x;
  int nth = gridDim.x*blockDim.x;
  // R1: TT64[r][i] = T[i][r] + (i==0 ? T[64][r] : 0)   (wrap-fold of spatial index)
  for (int idx = tid; idx < 4*64*17; idx += nth) {
    int w = idx/(64*17), rem = idx%(64*17), i = rem/17, m = rem%17;
    int r = w + 4*m;
    float v = 0.f;
    if (r < 65) v = (float)(Tval(i, r) + (i==0 ? Tval(64, r) : 0.0));
    g_R1[idx] = v;
  }
  // R2: T[r][i], r<64
  for (int idx = tid; idx < 4*65*16; idx += nth) {
    int w = idx/(65*16), rem = idx%(65*16), i = rem/16, m = rem%16;
    int r = w + 4*m;
    g_R2[idx] = (float)Tval(r, i);
  }
  // G1[j][t] = TT64[t][j]
  for (int idx = tid; idx < 64*65; idx += nth) {
    int j = idx/65, k = idx%65;
    g_G1[idx] = (float)(Tval(j, k) + (j==0 ? Tval(64, k) : 0.0));
  }
  // G2[k1][t] = T[t][k1]
  for (int idx = tid; idx < 65*64; idx += nth) {
    int k1 = idx/64, t2 = idx%64;
    g_G2[idx] = (float)Tval(t2, k1);
  }
  // Mp[k1][k2] = -n(k1)*n(k2) / (bf(k1)^2 + bf(k2)^2), (0,0)->0
  for (int idx = tid; idx < 65*65; idx += nth) {
    int k1 = idx/65, k2 = idx%65;
    float v = 0.f;
    if (k1 | k2) {
      double n1 = (k1==0)?(1.0/65.0):(2.0/65.0);
      double n2 = (k2==0)?(1.0/65.0):(2.0/65.0);
      int m1 = (k1<=32)?k1:(k1-32), m2 = (k2<=32)?k2:(k2-32);
      double b1 = 6.283185307179586476925286766559*(double)m1/65.0;
      double b2 = 6.283185307179586476925286766559*(double)m2/65.0;
      v = (float)(-(n1*n2)/(b1*b1 + b2*b2));
    }
    g_Mp[idx] = v;
  }
}

// One matmul stage: out[r][c] = sum_i Tbl[r][i] * Lb[i][c], wave owns rows r=wv+4m,
// lane = column c (0..63). Transposed LDS write Ob[c*65+r] (stride 65, odd -> no bank conflict).
template<int K, int MPW, int ROWS, bool SCALE>
__device__ inline void mm_step(const float* __restrict__ tbl,
                               const float* __restrict__ Lb,
                               float* __restrict__ Ob,
                               int wvu, int lane)
{
  float acc[MPW];
  #pragma unroll
  for (int m=0;m<MPW;++m) acc[m] = 0.f;
  const float* tw = tbl + wvu*(K*MPW);   // wave-uniform -> s_load path
  #pragma unroll 4
  for (int i=0;i<K;++i) {
    float lv = Lb[i*P65 + lane];
    const float* ti = tw + i*MPW;
    #pragma unroll
    for (int m=0;m<MPW;++m) acc[m] = fmaf(ti[m], lv, acc[m]);
  }
  #pragma unroll
  for (int m=0;m<MPW;++m) {
    int r = wvu + 4*m;
    if (r < ROWS) {
      float v = acc[m];
      if (SCALE) v *= g_Mp[r*P65 + lane];
      Ob[lane*P65 + r] = v;
    }
  }
}

__global__ void __launch_bounds__(256) pde_main(const float* __restrict__ y0,
                                                const int*   __restrict__ env,
                                                const float* __restrict__ params,
                                                float*       __restrict__ out)
{
  __shared__ float BufW[P65*P65];   // holds -x (w), rows/cols 0..63 used
  __shared__ float BufA[P65*P65];
  __shared__ float BufB[P65*P65];

  const int b    = blockIdx.x;
  const int t    = threadIdx.x;
  const int lane = t & 63;
  const int wvu  = __builtin_amdgcn_readfirstlane(t >> 6);

  const int   e      = env[b];
  const float mu     = params[2*e];
  const float fdx    = c_DOMAIN[e] * (float)(3.14159265358979323846/64.0);
  const float inv_dx2 = 1.0f/(fdx*fdx);

  // ---- load w = -x into LDS ----
  const float* xb = y0 + (size_t)b*4096;
  for (int idx = t; idx < 4096; idx += 256) {
    int j = idx >> 6, c = idx & 63;
    BufW[j*P65 + c] = -xb[idx];
  }
  __syncthreads();

  // ---- step1: S1^T = (TT64 * W)^T -> BufA (rows j<64 used, cols k<65) ----
  mm_step<64,17,65,false>(g_R1, BufW, BufA, wvu, lane);
  __syncthreads();

  // ---- step2: B = M' .* (TT64 * S1^T)^T -> BufB ; tail computes row k1=64 ----
  mm_step<64,17,65,true>(g_R1, BufA, BufB, wvu, lane);
  if (t < 65) {
    float acc = 0.f;
    for (int j=0;j<64;++j) acc = fmaf(g_G1[j*P65 + t], BufA[j*P65 + 64], acc);
    BufB[64*P65 + t] = acc * g_Mp[64*P65 + t];
  }
  __syncthreads();

  // ---- step3: V^T = (T * B)^T -> BufA ; tail computes row k2=64 ----
  mm_step<65,16,64,false>(g_R2, BufB, BufA, wvu, lane);
  if (t < 64) {
    float acc = 0.f;
    for (int k1=0;k1<65;++k1) acc = fmaf(g_G2[k1*64 + t], BufB[k1*P65 + 64], acc);
    BufA[64*P65 + t] = acc;
  }
  __syncthreads();

  // ---- step4: psi = (T * V^T)^T -> BufB (normal orientation, rows/cols 0..63) ----
  mm_step<65,16,64,false>(g_R2, BufA, BufB, wvu, lane);
  __syncthreads();

  // ---- stencils. psi = dx^2 * P, and psi*inv4 = P*0.25 (dx cancels in Jacobians) ----
  for (int idx = t; idx < 4096; idx += 256) {
    int j = idx >> 6, c = idx & 63;
    int jm = (j+63)&63, jp = (j+1)&63;
    int cm = (c+63)&63, cp = (c+1)&63;
    #define XV(a,bb) (-BufW[(a)*P65 + (bb)])
    #define PV(a,bb) (BufB[(a)*P65 + (bb)])
    float x_c  = XV(j ,c );
    float x_jm = XV(jm,c ), x_jp = XV(jp,c );
    float x_cm = XV(j ,cm), x_cp = XV(j ,cp);
    float x_pp = XV(jp,cp), x_mm = XV(jm,cm);
    float x_pm = XV(jp,cm), x_mp = XV(jm,cp);
    float p_jm = PV(jm,c ), p_jp = PV(jp,c );
    float p_cm = PV(j ,cm), p_cp = PV(j ,cp);
    float p_pp = PV(jp,cp), p_mm = PV(jm,cm);
    float p_pm = PV(jp,cm), p_mp = PV(jm,cp);
    #undef XV
    #undef PV

    float J1 = (p_jp - p_jm)*(x_cp - x_cm) - (p_cp - p_cm)*(x_jp - x_jm);
    float J2 = x_cp*(p_pp - p_mp) - x_cm*(p_pm - p_mm)
             - x_jp*(p_pp - p_pm) + x_jm*(p_mp - p_mm);
    float J3 = x_pp*(p_jp - p_cp) - x_mm*(p_cm - p_jm)
             - x_pm*(p_jp - p_cm) + x_mp*(p_cp - p_jm);
    float lap = (x_jm + x_jp + x_cm + x_cp + x_pm - 4.0f*x_c) * inv_dx2;

    out[(size_t)b*4096 + idx] = -(J1 + J2 + J3)*(0.25f/3.0f) + mu*lap;
  }
}

extern "C" void kernel_launch(void* const* d_in, const int* in_sizes, int n_in,
                              void* d_out, int out_size, void* d_ws, size_t ws_size,
                              hipStream_t stream) {
  const float* y0     = (const float*)d_in[1];
  const int*   env    = (const int*)  d_in[2];
  const float* params = (const float*)d_in[3];
  float*       out    = (float*)d_out;
  int B = in_sizes[1] / 4096;

  init_tables<<<96, 256, 0, stream>>>();
  pde_main<<<B, 256, 0, stream>>>(y0, env, params, out);
}

// Round 2
// 100.544 us; speedup vs baseline: 1.2063x; 1.2063x over previous
//
#include <hip/hip_runtime.h>
#include <math.h>

// ---------------- constants ----------------
#define P65 65

// Precomputed operator tables (written by init_tables every launch; deterministic).
__device__ float g_R1[4*64*17];   // folded TT64 rearranged per-wave: [w][i<64][m<17], row r=w+4m (<65)
__device__ float g_R2[4*65*16];   // T rearranged per-wave:           [w][i<65][m<16], row r=w+4m (<64)
__device__ float g_G1[64*65];     // G1[j][t] = TT64[t][j]  (tail of step2)
__device__ float g_G2[65*64];     // G2[k1][t] = T[t][k1]   (tail of step3)
__device__ float g_Mp[65*65];     // spectral multiplier with analysis norms folded in; [0][0]=0

__device__ __constant__ float c_DOMAIN[8] = {0.75f,1.0f,0.75f,1.0f,0.75f,1.0f,0.75f,1.0f};

// T[j][k]: k<=32 -> cos(2*pi*j*k/65); k>=33 -> sin(2*pi*j*(k-32)/65)
__device__ inline double Tval(int j, int k) {
  int m = (k <= 32) ? k : (k - 32);
  int prod = (j * m) % 65;                 // exact modular reduction of the angle
  double ang = (6.283185307179586476925286766559 * (double)prod) / 65.0;
  return (k <= 32) ? cos(ang) : sin(ang);
}

__global__ void init_tables() {
  int tid = blockIdx.x*blockDim.x + threadIdx.x;
  int nth = gridDim.x*blockDim.x;
  // R1: TT64[r][i] = T[i][r] + (i==0 ? T[64][r] : 0)   (wrap-fold of spatial index)
  for (int idx = tid; idx < 4*64*17; idx += nth) {
    int w = idx/(64*17), rem = idx%(64*17), i = rem/17, m = rem%17;
    int r = w + 4*m;
    float v = 0.f;
    if (r < 65) v = (float)(Tval(i, r) + (i==0 ? Tval(64, r) : 0.0));
    g_R1[idx] = v;
  }
  // R2: T[r][i], r<64
  for (int idx = tid; idx < 4*65*16; idx += nth) {
    int w = idx/(65*16), rem = idx%(65*16), i = rem/16, m = rem%16;
    int r = w + 4*m;
    g_R2[idx] = (float)Tval(r, i);
  }
  // G1[j][t] = TT64[t][j]
  for (int idx = tid; idx < 64*65; idx += nth) {
    int j = idx/65, k = idx%65;
    g_G1[idx] = (float)(Tval(j, k) + (j==0 ? Tval(64, k) : 0.0));
  }
  // G2[k1][t] = T[t][k1]
  for (int idx = tid; idx < 65*64; idx += nth) {
    int k1 = idx/64, t2 = idx%64;
    g_G2[idx] = (float)Tval(t2, k1);
  }
  // Mp[k1][k2] = -n(k1)*n(k2) / (bf(k1)^2 + bf(k2)^2), (0,0)->0
  for (int idx = tid; idx < 65*65; idx += nth) {
    int k1 = idx/65, k2 = idx%65;
    float v = 0.f;
    if (k1 | k2) {
      double n1 = (k1==0)?(1.0/65.0):(2.0/65.0);
      double n2 = (k2==0)?(1.0/65.0):(2.0/65.0);
      int m1 = (k1<=32)?k1:(k1-32), m2 = (k2<=32)?k2:(k2-32);
      double b1 = 6.283185307179586476925286766559*(double)m1/65.0;
      double b2 = 6.283185307179586476925286766559*(double)m2/65.0;
      v = (float)(-(n1*n2)/(b1*b1 + b2*b2));
    }
    g_Mp[idx] = v;
  }
}

// One matmul stage: out[r][c] = sum_i Tbl[r][i] * Lb[i][c], wave owns rows r=wv+4m,
// lane = column c (0..63). Transposed LDS write Ob[c*65+r] (stride 65, odd -> no bank conflict).
template<int K, int MPW, int ROWS, bool SCALE>
__device__ inline void mm_step(const float* __restrict__ tbl,
                               const float* __restrict__ Lb,
                               float* __restrict__ Ob,
                               int wvu, int lane)
{
  float acc[MPW];
  #pragma unroll
  for (int m=0;m<MPW;++m) acc[m] = 0.f;
  const float* tw = tbl + wvu*(K*MPW);   // wave-uniform -> s_load path
  #pragma unroll 8
  for (int i=0;i<K;++i) {
    float lv = Lb[i*P65 + lane];
    const float* ti = tw + i*MPW;
    #pragma unroll
    for (int m=0;m<MPW;++m) acc[m] = fmaf(ti[m], lv, acc[m]);
  }
  #pragma unroll
  for (int m=0;m<MPW;++m) {
    int r = wvu + 4*m;
    if (r < ROWS) {
      float v = acc[m];
      if (SCALE) v *= g_Mp[r*P65 + lane];
      Ob[lane*P65 + r] = v;
    }
  }
}

__global__ void __launch_bounds__(256) pde_main(const float* __restrict__ y0,
                                                const int*   __restrict__ env,
                                                const float* __restrict__ params,
                                                float*       __restrict__ out)
{
  __shared__ float BufA[P65*P65];
  __shared__ float BufB[P65*P65];

  const int b    = blockIdx.x;
  const int t    = threadIdx.x;
  const int lane = t & 63;
  const int wvu  = __builtin_amdgcn_readfirstlane(t >> 6);

  const int   e      = env[b];
  const float mu     = params[2*e];
  const float fdx    = c_DOMAIN[e] * (float)(3.14159265358979323846/64.0);
  const float inv_dx2 = 1.0f/(fdx*fdx);

  // ---- load x; keep in registers; write w=-x into LDS A ----
  const float* xb = y0 + (size_t)b*4096;
  float xr[16];
  #pragma unroll
  for (int k=0;k<16;++k) {
    xr[k] = xb[k*256 + t];
    int j = k*4 + (t>>6);
    BufA[j*P65 + lane] = -xr[k];
  }
  __syncthreads();

  // ---- step1: S1^T = (TT64 * W)^T : A -> B ----
  mm_step<64,17,65,false>(g_R1, BufA, BufB, wvu, lane);
  __syncthreads();

  // ---- step2: Bspec = M' .* (TT64 * S1^T)^T : B -> A ; tail computes row k1=64 ----
  mm_step<64,17,65,true>(g_R1, BufB, BufA, wvu, lane);
  if (t < 65) {
    float acc = 0.f;
    for (int j=0;j<64;++j) acc = fmaf(g_G1[j*P65 + t], BufB[j*P65 + 64], acc);
    BufA[64*P65 + t] = acc * g_Mp[64*P65 + t];
  }
  __syncthreads();

  // ---- step3: V^T = (T * Bspec)^T : A -> B ; tail computes row k2=64 ----
  mm_step<65,16,64,false>(g_R2, BufA, BufB, wvu, lane);
  if (t < 64) {
    float acc = 0.f;
    for (int k1=0;k1<65;++k1) acc = fmaf(g_G2[k1*64 + t], BufA[k1*P65 + 64], acc);
    BufB[64*P65 + t] = acc;
  }
  __syncthreads();

  // ---- step4: psi = (T * V^T)^T : B -> A (psi in A, rows/cols 0..63) ----
  mm_step<65,16,64,false>(g_R2, BufB, BufA, wvu, lane);
  __syncthreads();

  // ---- replay x registers into freed B (no second global read) ----
  #pragma unroll
  for (int k=0;k<16;++k) {
    int j = k*4 + (t>>6);
    BufB[j*P65 + lane] = xr[k];
  }
  __syncthreads();

  // ---- stencils. psi = dx^2 * P, and psi*inv4 = P*0.25 (dx cancels in Jacobians) ----
  for (int idx = t; idx < 4096; idx += 256) {
    int j = idx >> 6, c = idx & 63;
    int jm = (j+63)&63, jp = (j+1)&63;
    int cm = (c+63)&63, cp = (c+1)&63;
    #define XV(a,bb) (BufB[(a)*P65 + (bb)])
    #define PV(a,bb) (BufA[(a)*P65 + (bb)])
    float x_c  = XV(j ,c );
    float x_jm = XV(jm,c ), x_jp = XV(jp,c );
    float x_cm = XV(j ,cm), x_cp = XV(j ,cp);
    float x_pp = XV(jp,cp), x_mm = XV(jm,cm);
    float x_pm = XV(jp,cm), x_mp = XV(jm,cp);
    float p_jm = PV(jm,c ), p_jp = PV(jp,c );
    float p_cm = PV(j ,cm), p_cp = PV(j ,cp);
    float p_pp = PV(jp,cp), p_mm = PV(jm,cm);
    float p_pm = PV(jp,cm), p_mp = PV(jm,cp);
    #undef XV
    #undef PV

    float J1 = (p_jp - p_jm)*(x_cp - x_cm) - (p_cp - p_cm)*(x_jp - x_jm);
    float J2 = x_cp*(p_pp - p_mp) - x_cm*(p_pm - p_mm)
             - x_jp*(p_pp - p_pm) + x_jm*(p_mp - p_mm);
    float J3 = x_pp*(p_jp - p_cp) - x_mm*(p_cm - p_jm)
             - x_pm*(p_jp - p_cm) + x_mp*(p_cp - p_jm);
    float lap = (x_jm + x_jp + x_cm + x_cp + x_pm - 4.0f*x_c) * inv_dx2;

    out[(size_t)b*4096 + idx] = -(J1 + J2 + J3)*(0.25f/3.0f) + mu*lap;
  }
}

extern "C" void kernel_launch(void* const* d_in, const int* in_sizes, int n_in,
                              void* d_out, int out_size, void* d_ws, size_t ws_size,
                              hipStream_t stream) {
  const float* y0     = (const float*)d_in[1];
  const int*   env    = (const int*)  d_in[2];
  const float* params = (const float*)d_in[3];
  float*       out    = (float*)d_out;
  int B = in_sizes[1] / 4096;

  init_tables<<<96, 256, 0, stream>>>();
  pde_main<<<B, 256, 0, stream>>>(y0, env, params, out);
}

// Round 3
// 85.942 us; speedup vs baseline: 1.4112x; 1.1699x over previous
//
#include <hip/hip_runtime.h>
#include <math.h>

// ---------------- constants ----------------
#define P65 65

// Precomputed operator tables (written by init_tables every launch; deterministic).
// 8-wave layout: wave w owns rows r = w + 8*m.
__device__ float g_R1[8*64*9];    // folded TT64 per-wave: [w][i<64][m<9], row r=w+8m (<65, else 0-pad)
__device__ float g_R2[8*65*8];    // T per-wave:           [w][i<65][m<8], row r=w+8m (<64)
__device__ float g_G1[64*65];     // G1[j][t] = TT64[t][j]  (tail of step2)
__device__ float g_G2[65*64];     // G2[k1][t] = T[t][k1]   (tail of step3)
__device__ float g_Mp[65*65];     // spectral multiplier with analysis norms folded in; [0][0]=0

__device__ __constant__ float c_DOMAIN[8] = {0.75f,1.0f,0.75f,1.0f,0.75f,1.0f,0.75f,1.0f};

// T[j][k]: k<=32 -> cos(2*pi*j*k/65); k>=33 -> sin(2*pi*j*(k-32)/65)
__device__ inline double Tval(int j, int k) {
  int m = (k <= 32) ? k : (k - 32);
  int prod = (j * m) % 65;                 // exact modular reduction of the angle
  double ang = (6.283185307179586476925286766559 * (double)prod) / 65.0;
  return (k <= 32) ? cos(ang) : sin(ang);
}

__global__ void init_tables() {
  int tid = blockIdx.x*blockDim.x + threadIdx.x;
  int nth = gridDim.x*blockDim.x;
  // R1: TT64[r][i] = T[i][r] + (i==0 ? T[64][r] : 0)   (wrap-fold of spatial index)
  for (int idx = tid; idx < 8*64*9; idx += nth) {
    int w = idx/(64*9), rem = idx%(64*9), i = rem/9, m = rem%9;
    int r = w + 8*m;
    float v = 0.f;
    if (r < 65) v = (float)(Tval(i, r) + (i==0 ? Tval(64, r) : 0.0));
    g_R1[idx] = v;
  }
  // R2: T[r][i], r<64
  for (int idx = tid; idx < 8*65*8; idx += nth) {
    int w = idx/(65*8), rem = idx%(65*8), i = rem/8, m = rem%8;
    int r = w + 8*m;
    g_R2[idx] = (float)Tval(r, i);
  }
  // G1[j][t] = TT64[t][j]
  for (int idx = tid; idx < 64*65; idx += nth) {
    int j = idx/65, k = idx%65;
    g_G1[idx] = (float)(Tval(j, k) + (j==0 ? Tval(64, k) : 0.0));
  }
  // G2[k1][t] = T[t][k1]
  for (int idx = tid; idx < 65*64; idx += nth) {
    int k1 = idx/64, t2 = idx%64;
    g_G2[idx] = (float)Tval(t2, k1);
  }
  // Mp[k1][k2] = -n(k1)*n(k2) / (bf(k1)^2 + bf(k2)^2), (0,0)->0
  for (int idx = tid; idx < 65*65; idx += nth) {
    int k1 = idx/65, k2 = idx%65;
    float v = 0.f;
    if (k1 | k2) {
      double n1 = (k1==0)?(1.0/65.0):(2.0/65.0);
      double n2 = (k2==0)?(1.0/65.0):(2.0/65.0);
      int m1 = (k1<=32)?k1:(k1-32), m2 = (k2<=32)?k2:(k2-32);
      double b1 = 6.283185307179586476925286766559*(double)m1/65.0;
      double b2 = 6.283185307179586476925286766559*(double)m2/65.0;
      v = (float)(-(n1*n2)/(b1*b1 + b2*b2));
    }
    g_Mp[idx] = v;
  }
}

// One matmul stage: out[r][c] = sum_i Tbl[r][i] * Lb[i][c], wave owns rows r=wv+8m,
// lane = column c (0..63). Transposed LDS write Ob[c*65+r] (stride 65, odd -> no bank conflict).
template<int K, int MPW, int ROWS, bool SCALE>
__device__ inline void mm_step(const float* __restrict__ tbl,
                               const float* __restrict__ Lb,
                               float* __restrict__ Ob,
                               int wvu, int lane)
{
  float acc[MPW];
  #pragma unroll
  for (int m=0;m<MPW;++m) acc[m] = 0.f;
  const float* tw = tbl + wvu*(K*MPW);   // wave-uniform -> s_load path
  #pragma unroll 8
  for (int i=0;i<K;++i) {
    float lv = Lb[i*P65 + lane];
    const float* ti = tw + i*MPW;
    #pragma unroll
    for (int m=0;m<MPW;++m) acc[m] = fmaf(ti[m], lv, acc[m]);
  }
  #pragma unroll
  for (int m=0;m<MPW;++m) {
    int r = wvu + 8*m;
    if (r < ROWS) {
      float v = acc[m];
      if (SCALE) v *= g_Mp[r*P65 + lane];
      Ob[lane*P65 + r] = v;
    }
  }
}

__global__ void __launch_bounds__(512) pde_main(const float* __restrict__ y0,
                                                const int*   __restrict__ env,
                                                const float* __restrict__ params,
                                                float*       __restrict__ out)
{
  __shared__ float BufA[P65*P65];
  __shared__ float BufB[P65*P65];

  const int b    = blockIdx.x;
  const int t    = threadIdx.x;
  const int lane = t & 63;
  const int wvu  = __builtin_amdgcn_readfirstlane(t >> 6);

  const int   e      = env[b];
  const float mu     = params[2*e];
  const float fdx    = c_DOMAIN[e] * (float)(3.14159265358979323846/64.0);
  const float inv_dx2 = 1.0f/(fdx*fdx);

  // ---- load x; keep in registers; write w=-x into LDS A ----
  const float* xb = y0 + (size_t)b*4096;
  float xr[8];
  #pragma unroll
  for (int k=0;k<8;++k) {
    xr[k] = xb[k*512 + t];
    int j = k*8 + (t>>6);
    BufA[j*P65 + lane] = -xr[k];
  }
  __syncthreads();

  // ---- step1: S1^T = (TT64 * W)^T : A -> B ----
  mm_step<64,9,65,false>(g_R1, BufA, BufB, wvu, lane);
  __syncthreads();

  // ---- step2: Bspec = M' .* (TT64 * S1^T)^T : B -> A ; tail computes row k1=64 ----
  mm_step<64,9,65,true>(g_R1, BufB, BufA, wvu, lane);
  if (t < 65) {
    float acc = 0.f;
    for (int j=0;j<64;++j) acc = fmaf(g_G1[j*P65 + t], BufB[j*P65 + 64], acc);
    BufA[64*P65 + t] = acc * g_Mp[64*P65 + t];
  }
  __syncthreads();

  // ---- step3: V^T = (T * Bspec)^T : A -> B ; tail computes row k2=64 ----
  mm_step<65,8,64,false>(g_R2, BufA, BufB, wvu, lane);
  if (t < 64) {
    float acc = 0.f;
    for (int k1=0;k1<65;++k1) acc = fmaf(g_G2[k1*64 + t], BufA[k1*P65 + 64], acc);
    BufB[64*P65 + t] = acc;
  }
  __syncthreads();

  // ---- step4: psi = (T * V^T)^T : B -> A (psi in A, rows/cols 0..63) ----
  mm_step<65,8,64,false>(g_R2, BufB, BufA, wvu, lane);
  __syncthreads();

  // ---- replay x registers into freed B (no second global read) ----
  #pragma unroll
  for (int k=0;k<8;++k) {
    int j = k*8 + (t>>6);
    BufB[j*P65 + lane] = xr[k];
  }
  __syncthreads();

  // ---- stencils. psi = dx^2 * P, and psi*inv4 = P*0.25 (dx cancels in Jacobians) ----
  for (int idx = t; idx < 4096; idx += 512) {
    int j = idx >> 6, c = idx & 63;
    int jm = (j+63)&63, jp = (j+1)&63;
    int cm = (c+63)&63, cp = (c+1)&63;
    #define XV(a,bb) (BufB[(a)*P65 + (bb)])
    #define PV(a,bb) (BufA[(a)*P65 + (bb)])
    float x_c  = XV(j ,c );
    float x_jm = XV(jm,c ), x_jp = XV(jp,c );
    float x_cm = XV(j ,cm), x_cp = XV(j ,cp);
    float x_pp = XV(jp,cp), x_mm = XV(jm,cm);
    float x_pm = XV(jp,cm), x_mp = XV(jm,cp);
    float p_jm = PV(jm,c ), p_jp = PV(jp,c );
    float p_cm = PV(j ,cm), p_cp = PV(j ,cp);
    float p_pp = PV(jp,cp), p_mm = PV(jm,cm);
    float p_pm = PV(jp,cm), p_mp = PV(jm,cp);
    #undef XV
    #undef PV

    float J1 = (p_jp - p_jm)*(x_cp - x_cm) - (p_cp - p_cm)*(x_jp - x_jm);
    float J2 = x_cp*(p_pp - p_mp) - x_cm*(p_pm - p_mm)
             - x_jp*(p_pp - p_pm) + x_jm*(p_mp - p_mm);
    float J3 = x_pp*(p_jp - p_cp) - x_mm*(p_cm - p_jm)
             - x_pm*(p_jp - p_cm) + x_mp*(p_cp - p_jm);
    float lap = (x_jm + x_jp + x_cm + x_cp + x_pm - 4.0f*x_c) * inv_dx2;

    out[(size_t)b*4096 + idx] = -(J1 + J2 + J3)*(0.25f/3.0f) + mu*lap;
  }
}

extern "C" void kernel_launch(void* const* d_in, const int* in_sizes, int n_in,
                              void* d_out, int out_size, void* d_ws, size_t ws_size,
                              hipStream_t stream) {
  const float* y0     = (const float*)d_in[1];
  const int*   env    = (const int*)  d_in[2];
  const float* params = (const float*)d_in[3];
  float*       out    = (float*)d_out;
  int B = in_sizes[1] / 4096;

  init_tables<<<96, 256, 0, stream>>>();
  pde_main<<<B, 512, 0, stream>>>(y0, env, params, out);
}

// Round 4
// 79.691 us; speedup vs baseline: 1.5219x; 1.0784x over previous
//
#include <hip/hip_runtime.h>
#include <math.h>

#define P65 65

// ---- Parity-split operator tables (device-built each launch; deterministic) ----
// Cos half: 33 rows (freq m=0..32), K=33 over even-part rows 0..32.
//   Packed per wave w=0..3: rows r=w+4m', m'=0..8 (r<=32 valid else 0).
// Sin half: 32 rows (freq m=1..32 stored at 32+m), K=32 over odd-part rows 33..64.
//   Packed per wave w'=0..3: rows mf=w'+4m'+1, m'=0..7.
__device__ float g_Rc[4*33*9];   // [w][i<33][m<9] : cos(2*pi*i*r/65), i==0 -> 1
__device__ float g_Rs[4*32*8];   // [w][i<32][m<8] : sin(2*pi*(i+1)*mf/65)
__device__ float g_G [65*33];    // full parity table for col-64 tails
__device__ float g_Mp[65*65];    // spectral multiplier (norms folded); [0][0]=0

__device__ __constant__ float c_DOMAIN[8] = {0.75f,1.0f,0.75f,1.0f,0.75f,1.0f,0.75f,1.0f};

__device__ inline double ctab(int a, int b) {           // cos(2*pi*a*b/65)
  int prod = (a*b) % 65;
  return cos(6.283185307179586476925286766559 * (double)prod / 65.0);
}
__device__ inline double stab(int a, int b) {           // sin(2*pi*a*b/65)
  int prod = (a*b) % 65;
  return sin(6.283185307179586476925286766559 * (double)prod / 65.0);
}

__global__ void init_tables() {
  int tid = blockIdx.x*blockDim.x + threadIdx.x;
  int nth = gridDim.x*blockDim.x;
  for (int idx = tid; idx < 4*33*9; idx += nth) {
    int w = idx/(33*9), rem = idx%(33*9), i = rem/9, m = rem%9;
    int r = w + 4*m;
    g_Rc[idx] = (r <= 32) ? (float)((i==0) ? 1.0 : ctab(i, r)) : 0.f;
  }
  for (int idx = tid; idx < 4*32*8; idx += nth) {
    int w = idx/(32*8), rem = idx%(32*8), i = rem/8, m = rem%8;
    int mf = w + 4*m + 1;
    g_Rs[idx] = (float)stab(i+1, mf);
  }
  for (int idx = tid; idx < 65*33; idx += nth) {
    int r = idx/33, i = idx%33;
    float v;
    if (r <= 32) v = (i==0) ? 1.f : (float)ctab(i, r);
    else         v = (i==0) ? 0.f : (float)stab(i, r-32);
    g_G[idx] = v;
  }
  for (int idx = tid; idx < 65*65; idx += nth) {
    int k1 = idx/65, k2 = idx%65;
    float v = 0.f;
    if (k1 | k2) {
      double n1 = (k1==0)?(1.0/65.0):(2.0/65.0);
      double n2 = (k2==0)?(1.0/65.0):(2.0/65.0);
      int m1 = (k1<=32)?k1:(k1-32), m2 = (k2<=32)?k2:(k2-32);
      double b1 = 6.283185307179586476925286766559*(double)m1/65.0;
      double b2 = 6.283185307179586476925286766559*(double)m2/65.0;
      v = (float)(-(n1*n2)/(b1*b1 + b2*b2));
    }
    g_Mp[idx] = v;
  }
}

// Half-matmul: out[r][lane] = sum_i tbl[r][i] * Lb[inBase+i][lane], transposed write.
// SIN=false: K=33, MPW=9, rows r=w4+4m (<=32), input rows 0..32.
// SIN=true : K=32, MPW=8, rows r=33+w4+4m, input rows 33..64.
template<int K, int MPW, bool SIN, bool SCALE>
__device__ inline void mm_half(const float* __restrict__ tw,
                               const float* __restrict__ Lb,
                               float* __restrict__ Ob,
                               int w4, int lane)
{
  float acc[MPW];
  #pragma unroll
  for (int m=0;m<MPW;++m) acc[m] = 0.f;
  const int inBase = SIN ? 33 : 0;
  #pragma unroll 8
  for (int i=0;i<K;++i) {
    float lv = Lb[(inBase+i)*P65 + lane];
    const float* ti = tw + i*MPW;
    #pragma unroll
    for (int m=0;m<MPW;++m) acc[m] = fmaf(ti[m], lv, acc[m]);
  }
  #pragma unroll
  for (int m=0;m<MPW;++m) {
    int r = SIN ? (33 + w4 + 4*m) : (w4 + 4*m);
    if (SIN || r <= 32) {
      float v = acc[m];
      if (SCALE) v *= g_Mp[r*P65 + lane];
      Ob[lane*P65 + r] = v;
    }
  }
}

template<bool SCALE>
__device__ inline void mm_stage(const float* __restrict__ Lb, float* __restrict__ Ob,
                                int wvu, int lane)
{
  if (wvu < 4) mm_half<33,9,false,SCALE>(g_Rc + wvu*(33*9), Lb, Ob, wvu, lane);
  else         mm_half<32,8,true ,SCALE>(g_Rs + (wvu-4)*(32*8), Lb, Ob, wvu-4, lane);
}

__global__ void __launch_bounds__(512) pde_main(const float* __restrict__ y0,
                                                const int*   __restrict__ env,
                                                const float* __restrict__ params,
                                                float*       __restrict__ out)
{
  __shared__ float A[P65*P65];
  __shared__ float B[P65*P65];

  const int b    = blockIdx.x;
  const int t    = threadIdx.x;
  const int lane = t & 63;
  const int wvu  = __builtin_amdgcn_readfirstlane(t >> 6);

  const int   e       = env[b];
  const float mu      = params[2*e];
  const float fdx     = c_DOMAIN[e] * (float)(3.14159265358979323846/64.0);
  const float inv_dx2 = 1.0f/(fdx*fdx);

  // ---- load x -> regs; W = -x -> A ----
  const float* xb = y0 + (size_t)b*4096;
  float xr[8];
  #pragma unroll
  for (int k=0;k<8;++k) {
    xr[k] = xb[k*512 + t];
    A[(8*k + wvu)*P65 + lane] = -xr[k];
  }
  __syncthreads();

  // ---- EO1: parity fold over spatial rows (Wp[64]=Wp[0]) : A -> B, rows 0..64, cols 0..63 ----
  #pragma unroll
  for (int m=0;m<9;++m) {
    int r = wvu + 8*m;
    if (r <= 64) {
      float v;
      if (r == 0)      v = A[lane];
      else if (r <= 32){ int p = (r==1)?0:(65-r); v = A[r*P65+lane] + A[p*P65+lane]; }
      else             { int i = r-32; int p = (i==1)?0:(65-i); v = A[i*P65+lane] - A[p*P65+lane]; }
      B[r*P65 + lane] = v;
    }
  }
  __syncthreads();

  // ---- stage1 (dim-1 analysis): B -> A transposed: A[c2][k1], c2=0..63, k1=0..64 ----
  mm_stage<false>(B, A, wvu, lane);
  __syncthreads();

  // ---- EO2: parity fold over spatial cols : A -> B (rows 0..64, cols k1 incl. 64) ----
  #pragma unroll
  for (int m=0;m<9;++m) {
    int r = wvu + 8*m;
    if (r <= 64) {
      float v;
      if (r == 0)      v = A[lane];
      else if (r <= 32){ int p = (r==1)?0:(65-r); v = A[r*P65+lane] + A[p*P65+lane]; }
      else             { int i = r-32; int p = (i==1)?0:(65-i); v = A[i*P65+lane] - A[p*P65+lane]; }
      B[r*P65 + lane] = v;
    }
  }
  if (t < 65) {          // column k1=64
    int r = t; float v;
    if (r == 0)      v = A[0*P65 + 64];
    else if (r <= 32){ int p = (r==1)?0:(65-r); v = A[r*P65+64] + A[p*P65+64]; }
    else             { int i = r-32; int p = (i==1)?0:(65-i); v = A[i*P65+64] - A[p*P65+64]; }
    B[r*P65 + 64] = v;
  }
  __syncthreads();

  // ---- stage2 (dim-2 analysis, x Mp): B -> A transposed: A[k1][k2]; tail k1=64 row ----
  mm_stage<true>(B, A, wvu, lane);
  if (t < 65) {
    float acc = 0.f;
    if (t <= 32) { for (int i=0;i<33;++i)  acc = fmaf(g_G[t*33+i], B[i*P65+64], acc); }
    else         { for (int i=1;i<33;++i)  acc = fmaf(g_G[t*33+i], B[(32+i)*P65+64], acc); }
    A[64*P65 + t] = acc * g_Mp[64*P65 + t];
  }
  __syncthreads();

  // ---- stage3 (dim-1 synthesis halves): A -> B transposed: B[k2][r'], tail k2=64 ----
  mm_stage<false>(A, B, wvu, lane);
  if (t < 65) {
    float acc = 0.f;
    if (t <= 32) { for (int i=0;i<33;++i)  acc = fmaf(g_G[t*33+i], A[i*P65+64], acc); }
    else         { for (int i=1;i<33;++i)  acc = fmaf(g_G[t*33+i], A[(32+i)*P65+64], acc); }
    B[64*P65 + t] = acc;
  }
  __syncthreads();

  // ---- combine3: B[k2][r'] -> A[k2][j1], j1=0..63, rows k2=0..64 ----
  #pragma unroll
  for (int m=0;m<9;++m) {
    int r = wvu + 8*m;
    if (r <= 64) {
      int j1 = lane; float v;
      if (j1 == 0)      v = B[r*P65];
      else if (j1 <= 32) v = B[r*P65 + j1] + B[r*P65 + 32 + j1];
      else               v = B[r*P65 + 65 - j1] - B[r*P65 + 97 - j1];
      A[r*P65 + lane] = v;
    }
  }
  __syncthreads();

  // ---- stage4 (dim-2 synthesis halves): A -> B transposed: B[j1][r''], j1=0..63 ----
  mm_stage<false>(A, B, wvu, lane);
  __syncthreads();

  // ---- combine4: B[j1][r''] -> psi in A[j1][j2], rows 0..63 ----
  #pragma unroll
  for (int m=0;m<8;++m) {
    int r = wvu + 8*m;
    int j2 = lane; float v;
    if (j2 == 0)      v = B[r*P65];
    else if (j2 <= 32) v = B[r*P65 + j2] + B[r*P65 + 32 + j2];
    else               v = B[r*P65 + 65 - j2] - B[r*P65 + 97 - j2];
    A[r*P65 + lane] = v;
  }
  __syncthreads();

  // ---- replay x registers into B ----
  #pragma unroll
  for (int k=0;k<8;++k) B[(8*k + wvu)*P65 + lane] = xr[k];
  __syncthreads();

  // ---- stencil: wave wvu owns rows 8*wvu..8*wvu+7, rolling 3-row window ----
  {
    const int c = lane, cm = (c+63)&63, cp = (c+1)&63;
    const int j0 = wvu*8;
    const int jm0 = (j0+63)&63;
    float xm_m = B[jm0*P65+cm], xm_c = B[jm0*P65+c], xm_p = B[jm0*P65+cp];
    float pm_m = A[jm0*P65+cm], pm_c = A[jm0*P65+c], pm_p = A[jm0*P65+cp];
    float xc_m = B[j0 *P65+cm], xc_c = B[j0 *P65+c], xc_p = B[j0 *P65+cp];
    float pc_m = A[j0 *P65+cm], pc_c = A[j0 *P65+c], pc_p = A[j0 *P65+cp];
    #pragma unroll
    for (int m=0;m<8;++m) {
      int j = j0 + m; int jp = (j+1)&63;
      float xn_m = B[jp*P65+cm], xn_c = B[jp*P65+c], xn_p = B[jp*P65+cp];
      float pn_m = A[jp*P65+cm], pn_c = A[jp*P65+c], pn_p = A[jp*P65+cp];

      float J1 = (pn_c - pm_c)*(xc_p - xc_m) - (pc_p - pc_m)*(xn_c - xm_c);
      float J2 = xc_p*(pn_p - pm_p) - xc_m*(pn_m - pm_m)
               - xn_c*(pn_p - pn_m) + xm_c*(pm_p - pm_m);
      float J3 = xn_p*(pn_c - pc_p) - xm_m*(pc_m - pm_c)
               - xn_m*(pn_c - pc_m) + xm_p*(pc_p - pm_c);
      float lap = (xm_c + xn_c + xc_m + xc_p + xn_m - 4.0f*xc_c) * inv_dx2;

      out[(size_t)b*4096 + j*64 + c] = -(J1 + J2 + J3)*(0.25f/3.0f) + mu*lap;

      xm_m=xc_m; xm_c=xc_c; xm_p=xc_p;  pm_m=pc_m; pm_c=pc_c; pm_p=pc_p;
      xc_m=xn_m; xc_c=xn_c; xc_p=xn_p;  pc_m=pn_m; pc_c=pn_c; pc_p=pn_p;
    }
  }
}

extern "C" void kernel_launch(void* const* d_in, const int* in_sizes, int n_in,
                              void* d_out, int out_size, void* d_ws, size_t ws_size,
                              hipStream_t stream) {
  const float* y0     = (const float*)d_in[1];
  const int*   env    = (const int*)  d_in[2];
  const float* params = (const float*)d_in[3];
  float*       out    = (float*)d_out;
  int B = in_sizes[1] / 4096;

  init_tables<<<96, 256, 0, stream>>>();
  pde_main<<<B, 512, 0, stream>>>(y0, env, params, out);
}

// Round 5
// 73.546 us; speedup vs baseline: 1.6491x; 1.0835x over previous
//
#include <hip/hip_runtime.h>
#include <math.h>

#define P65 65

// ---- Parity-split operator tables (device-built each launch; deterministic) ----
__device__ float g_Rc[4*33*9];   // [w][i<33][m<9] : cos(2*pi*i*r/65), i==0 -> 1 ; rows r=w+4m (<=32)
__device__ float g_Rs[4*32*8];   // [w][i<32][m<8] : sin(2*pi*(i+1)*mf/65)      ; rows mf=w+4m+1
__device__ float g_G [65*33];    // full parity table for col-64 tails
__device__ float g_Mp[65*65];    // spectral multiplier (norms folded); [0][0]=0

__device__ __constant__ float c_DOMAIN[8] = {0.75f,1.0f,0.75f,1.0f,0.75f,1.0f,0.75f,1.0f};

__device__ inline double ctab(int a, int b) {           // cos(2*pi*a*b/65)
  int prod = (a*b) % 65;
  return cos(6.283185307179586476925286766559 * (double)prod / 65.0);
}
__device__ inline double stab(int a, int b) {           // sin(2*pi*a*b/65)
  int prod = (a*b) % 65;
  return sin(6.283185307179586476925286766559 * (double)prod / 65.0);
}

__global__ void init_tables() {
  int tid = blockIdx.x*blockDim.x + threadIdx.x;
  int nth = gridDim.x*blockDim.x;
  for (int idx = tid; idx < 4*33*9; idx += nth) {
    int w = idx/(33*9), rem = idx%(33*9), i = rem/9, m = rem%9;
    int r = w + 4*m;
    g_Rc[idx] = (r <= 32) ? (float)((i==0) ? 1.0 : ctab(i, r)) : 0.f;
  }
  for (int idx = tid; idx < 4*32*8; idx += nth) {
    int w = idx/(32*8), rem = idx%(32*8), i = rem/8, m = rem%8;
    int mf = w + 4*m + 1;
    g_Rs[idx] = (float)stab(i+1, mf);
  }
  for (int idx = tid; idx < 65*33; idx += nth) {
    int r = idx/33, i = idx%33;
    float v;
    if (r <= 32) v = (i==0) ? 1.f : (float)ctab(i, r);
    else         v = (i==0) ? 0.f : (float)stab(i, r-32);
    g_G[idx] = v;
  }
  for (int idx = tid; idx < 65*65; idx += nth) {
    int k1 = idx/65, k2 = idx%65;
    float v = 0.f;
    if (k1 | k2) {
      double n1 = (k1==0)?(1.0/65.0):(2.0/65.0);
      double n2 = (k2==0)?(1.0/65.0):(2.0/65.0);
      int m1 = (k1<=32)?k1:(k1-32), m2 = (k2<=32)?k2:(k2-32);
      double b1 = 6.283185307179586476925286766559*(double)m1/65.0;
      double b2 = 6.283185307179586476925286766559*(double)m2/65.0;
      v = (float)(-(n1*n2)/(b1*b1 + b2*b2));
    }
    g_Mp[idx] = v;
  }
}

// Dual-image half-matmul: contracts over rows of L0/L1, transposed write to O0/O1.
// Table values feed both images' FMA chains (2x arithmetic per s_load).
template<int K, int MPW, bool SIN, bool SCALE>
__device__ inline void mm_half2(const float* __restrict__ tw,
                                const float* __restrict__ L0,
                                const float* __restrict__ L1,
                                float* __restrict__ O0,
                                float* __restrict__ O1,
                                int w4, int lane)
{
  float a0[MPW], a1[MPW];
  #pragma unroll
  for (int m=0;m<MPW;++m) { a0[m] = 0.f; a1[m] = 0.f; }
  const int inBase = SIN ? 33 : 0;
  #pragma unroll 4
  for (int i=0;i<K;++i) {
    float lv0 = L0[(inBase+i)*P65 + lane];
    float lv1 = L1[(inBase+i)*P65 + lane];
    const float* ti = tw + i*MPW;
    #pragma unroll
    for (int m=0;m<MPW;++m) {
      float tv = ti[m];
      a0[m] = fmaf(tv, lv0, a0[m]);
      a1[m] = fmaf(tv, lv1, a1[m]);
    }
  }
  #pragma unroll
  for (int m=0;m<MPW;++m) {
    int r = SIN ? (33 + w4 + 4*m) : (w4 + 4*m);
    if (SIN || r <= 32) {
      float v0 = a0[m], v1 = a1[m];
      if (SCALE) { float mp = g_Mp[r*P65 + lane]; v0 *= mp; v1 *= mp; }
      O0[lane*P65 + r] = v0;
      O1[lane*P65 + r] = v1;
    }
  }
}

template<bool SCALE>
__device__ inline void mm_stage2(const float* __restrict__ L0, const float* __restrict__ L1,
                                 float* __restrict__ O0, float* __restrict__ O1,
                                 int wvu, int lane)
{
  if (wvu < 4) mm_half2<33,9,false,SCALE>(g_Rc + wvu*(33*9), L0, L1, O0, O1, wvu, lane);
  else         mm_half2<32,8,true ,SCALE>(g_Rs + (wvu-4)*(32*8), L0, L1, O0, O1, wvu-4, lane);
}

// Parity fold read (analysis EO pass): even rows 0..32, odd rows 33..64.
__device__ inline float eo_fold(const float* __restrict__ Ab, int r, int lane) {
  if (r == 0) return Ab[lane];
  if (r <= 32) { int p = (r==1)?0:(65-r); return Ab[r*P65+lane] + Ab[p*P65+lane]; }
  int i = r-32; int p = (i==1)?0:(65-i); return Ab[i*P65+lane] - Ab[p*P65+lane];
}

__global__ void __launch_bounds__(512) pde_main(const float* __restrict__ y0,
                                                const int*   __restrict__ env,
                                                const float* __restrict__ params,
                                                float*       __restrict__ out,
                                                int B)
{
  __shared__ float A0[P65*P65];
  __shared__ float B0[P65*P65];
  __shared__ float A1[P65*P65];
  __shared__ float B1[P65*P65];

  const int t    = threadIdx.x;
  const int lane = t & 63;
  const int wvu  = __builtin_amdgcn_readfirstlane(t >> 6);

  const int b0 = 2*blockIdx.x;
  const int b1r = 2*blockIdx.x + 1;
  const bool has2 = (b1r < B);
  const int b1 = has2 ? b1r : b0;

  const int   e0 = env[b0], e1 = env[b1];
  const float mu0 = params[2*e0], mu1 = params[2*e1];
  const float fdx0 = c_DOMAIN[e0] * (float)(3.14159265358979323846/64.0);
  const float fdx1 = c_DOMAIN[e1] * (float)(3.14159265358979323846/64.0);
  const float idx2_0 = 1.0f/(fdx0*fdx0);
  const float idx2_1 = 1.0f/(fdx1*fdx1);

  // ---- load x -> regs; W = -x -> A ----
  const float* xb0 = y0 + (size_t)b0*4096;
  const float* xb1 = y0 + (size_t)b1*4096;
  float xr0[8], xr1[8];
  #pragma unroll
  for (int k=0;k<8;++k) {
    xr0[k] = xb0[k*512 + t];
    xr1[k] = xb1[k*512 + t];
    A0[(8*k + wvu)*P65 + lane] = -xr0[k];
    A1[(8*k + wvu)*P65 + lane] = -xr1[k];
  }
  __syncthreads();

  // ---- EO1: parity fold over spatial rows : A -> B ----
  #pragma unroll
  for (int m=0;m<9;++m) {
    int r = wvu + 8*m;
    if (r <= 64) {
      B0[r*P65 + lane] = eo_fold(A0, r, lane);
      B1[r*P65 + lane] = eo_fold(A1, r, lane);
    }
  }
  __syncthreads();

  // ---- stage1 (dim-1 analysis): B -> A transposed ----
  mm_stage2<false>(B0, B1, A0, A1, wvu, lane);
  __syncthreads();

  // ---- EO2: parity fold over spatial cols : A -> B (+ col 64 tail) ----
  #pragma unroll
  for (int m=0;m<9;++m) {
    int r = wvu + 8*m;
    if (r <= 64) {
      B0[r*P65 + lane] = eo_fold(A0, r, lane);
      B1[r*P65 + lane] = eo_fold(A1, r, lane);
    }
  }
  if (t < 65) {
    int r = t;
    float v0, v1;
    if (r == 0)      { v0 = A0[64]; v1 = A1[64]; }
    else if (r <= 32){ int p = (r==1)?0:(65-r); v0 = A0[r*P65+64] + A0[p*P65+64]; v1 = A1[r*P65+64] + A1[p*P65+64]; }
    else             { int i = r-32; int p = (i==1)?0:(65-i); v0 = A0[i*P65+64] - A0[p*P65+64]; v1 = A1[i*P65+64] - A1[p*P65+64]; }
    B0[r*P65 + 64] = v0;
    B1[r*P65 + 64] = v1;
  }
  __syncthreads();

  // ---- stage2 (dim-2 analysis, x Mp): B -> A transposed; tail k1=64 row ----
  mm_stage2<true>(B0, B1, A0, A1, wvu, lane);
  if (t < 65) {
    float acc0 = 0.f, acc1 = 0.f;
    if (t <= 32) {
      for (int i=0;i<33;++i) { float g = g_G[t*33+i]; acc0 = fmaf(g, B0[i*P65+64], acc0); acc1 = fmaf(g, B1[i*P65+64], acc1); }
    } else {
      for (int i=1;i<33;++i) { float g = g_G[t*33+i]; acc0 = fmaf(g, B0[(32+i)*P65+64], acc0); acc1 = fmaf(g, B1[(32+i)*P65+64], acc1); }
    }
    float mp = g_Mp[64*P65 + t];
    A0[64*P65 + t] = acc0 * mp;
    A1[64*P65 + t] = acc1 * mp;
  }
  __syncthreads();

  // ---- stage3 (dim-1 synthesis halves): A -> B transposed; tail k2=64 ----
  mm_stage2<false>(A0, A1, B0, B1, wvu, lane);
  if (t < 65) {
    float acc0 = 0.f, acc1 = 0.f;
    if (t <= 32) {
      for (int i=0;i<33;++i) { float g = g_G[t*33+i]; acc0 = fmaf(g, A0[i*P65+64], acc0); acc1 = fmaf(g, A1[i*P65+64], acc1); }
    } else {
      for (int i=1;i<33;++i) { float g = g_G[t*33+i]; acc0 = fmaf(g, A0[(32+i)*P65+64], acc0); acc1 = fmaf(g, A1[(32+i)*P65+64], acc1); }
    }
    B0[64*P65 + t] = acc0;
    B1[64*P65 + t] = acc1;
  }
  __syncthreads();

  // ---- combine3: B[k2][r'] -> A[k2][j1] ----
  #pragma unroll
  for (int m=0;m<9;++m) {
    int r = wvu + 8*m;
    if (r <= 64) {
      int j1 = lane; float v0, v1;
      if (j1 == 0)      { v0 = B0[r*P65]; v1 = B1[r*P65]; }
      else if (j1 <= 32){ v0 = B0[r*P65 + j1] + B0[r*P65 + 32 + j1]; v1 = B1[r*P65 + j1] + B1[r*P65 + 32 + j1]; }
      else              { v0 = B0[r*P65 + 65 - j1] - B0[r*P65 + 97 - j1]; v1 = B1[r*P65 + 65 - j1] - B1[r*P65 + 97 - j1]; }
      A0[r*P65 + lane] = v0;
      A1[r*P65 + lane] = v1;
    }
  }
  __syncthreads();

  // ---- stage4 (dim-2 synthesis halves): A -> B transposed ----
  mm_stage2<false>(A0, A1, B0, B1, wvu, lane);
  __syncthreads();

  // ---- combine4: B[j1][r''] -> psi in A[j1][j2] ----
  #pragma unroll
  for (int m=0;m<8;++m) {
    int r = wvu + 8*m;
    int j2 = lane; float v0, v1;
    if (j2 == 0)      { v0 = B0[r*P65]; v1 = B1[r*P65]; }
    else if (j2 <= 32){ v0 = B0[r*P65 + j2] + B0[r*P65 + 32 + j2]; v1 = B1[r*P65 + j2] + B1[r*P65 + 32 + j2]; }
    else              { v0 = B0[r*P65 + 65 - j2] - B0[r*P65 + 97 - j2]; v1 = B1[r*P65 + 65 - j2] - B1[r*P65 + 97 - j2]; }
    A0[r*P65 + lane] = v0;
    A1[r*P65 + lane] = v1;
  }
  __syncthreads();

  // ---- replay x registers into B ----
  #pragma unroll
  for (int k=0;k<8;++k) {
    B0[(8*k + wvu)*P65 + lane] = xr0[k];
    B1[(8*k + wvu)*P65 + lane] = xr1[k];
  }
  __syncthreads();

  // ---- stencil: wave wvu owns rows 8*wvu..8*wvu+7; rolling 3-row window; 2 images ----
  #pragma unroll 2
  for (int img = 0; img < 2; ++img) {
    const float* Ax = img ? A1 : A0;   // psi (P = psi/dx^2)
    const float* Bx = img ? B1 : B0;   // x
    const float muX  = img ? mu1 : mu0;
    const float id2  = img ? idx2_1 : idx2_0;
    float* op = out + (size_t)(img ? b1 : b0)*4096;
    const bool st = (img == 0) || has2;

    const int c = lane, cm = (c+63)&63, cp = (c+1)&63;
    const int j0 = wvu*8;
    const int jm0 = (j0+63)&63;
    float xm_m = Bx[jm0*P65+cm], xm_c = Bx[jm0*P65+c], xm_p = Bx[jm0*P65+cp];
    float pm_m = Ax[jm0*P65+cm], pm_c = Ax[jm0*P65+c], pm_p = Ax[jm0*P65+cp];
    float xc_m = Bx[j0 *P65+cm], xc_c = Bx[j0 *P65+c], xc_p = Bx[j0 *P65+cp];
    float pc_m = Ax[j0 *P65+cm], pc_c = Ax[j0 *P65+c], pc_p = Ax[j0 *P65+cp];
    #pragma unroll
    for (int m=0;m<8;++m) {
      int j = j0 + m; int jp = (j+1)&63;
      float xn_m = Bx[jp*P65+cm], xn_c = Bx[jp*P65+c], xn_p = Bx[jp*P65+cp];
      float pn_m = Ax[jp*P65+cm], pn_c = Ax[jp*P65+c], pn_p = Ax[jp*P65+cp];

      float J1 = (pn_c - pm_c)*(xc_p - xc_m) - (pc_p - pc_m)*(xn_c - xm_c);
      float J2 = xc_p*(pn_p - pm_p) - xc_m*(pn_m - pm_m)
               - xn_c*(pn_p - pn_m) + xm_c*(pm_p - pm_m);
      float J3 = xn_p*(pn_c - pc_p) - xm_m*(pc_m - pm_c)
               - xn_m*(pn_c - pc_m) + xm_p*(pc_p - pm_c);
      float lap = (xm_c + xn_c + xc_m + xc_p + xn_m - 4.0f*xc_c) * id2;

      if (st) op[j*64 + c] = -(J1 + J2 + J3)*(0.25f/3.0f) + muX*lap;

      xm_m=xc_m; xm_c=xc_c; xm_p=xc_p;  pm_m=pc_m; pm_c=pc_c; pm_p=pc_p;
      xc_m=xn_m; xc_c=xn_c; xc_p=xn_p;  pc_m=pn_m; pc_c=pn_c; pc_p=pn_p;
    }
  }
}

extern "C" void kernel_launch(void* const* d_in, const int* in_sizes, int n_in,
                              void* d_out, int out_size, void* d_ws, size_t ws_size,
                              hipStream_t stream) {
  const float* y0     = (const float*)d_in[1];
  const int*   env    = (const int*)  d_in[2];
  const float* params = (const float*)d_in[3];
  float*       out    = (float*)d_out;
  int B = in_sizes[1] / 4096;
  int nb = (B + 1) / 2;

  init_tables<<<96, 256, 0, stream>>>();
  pde_main<<<nb, 512, 0, stream>>>(y0, env, params, out, B);
}